// Round 1
// baseline (404.121 us; speedup 1.0000x reference)
//
#include <hip/hip_runtime.h>
#include <math.h>

// Problem constants
#define B_  16
#define C_  64
#define HW_ 128
#define E_  5

// ws layout (float offsets)
//   0        : wEff   [5][ci=64][tap=9][co=64]   (184320 floats)
//   184320   : biasEff[5][64]                    (320 floats)
//   184640   : pooled [16][64]                   (1024 floats)
//   185664   : Z      [16]                       (16 floats)
//   185680   : expert_idx [16] (int)
#define WS_WEFF   0
#define WS_BIAS   184320
#define WS_POOL   184640
#define WS_Z      185664
#define WS_EIDX   185680

// ---------------------------------------------------------------------------
// Kernel A: per-(b,c) mean over 128x128
__global__ void pool_kernel(const float* __restrict__ x, float* __restrict__ pooled) {
    int bc = blockIdx.x;  // 0..1023
    const float4* p = (const float4*)(x + (size_t)bc * 16384);
    float s = 0.f;
    for (int i = threadIdx.x; i < 4096; i += 256) {
        float4 v = p[i];
        s += v.x + v.y + v.z + v.w;
    }
    for (int off = 32; off; off >>= 1) s += __shfl_down(s, off, 64);
    __shared__ float ls[4];
    int lane = threadIdx.x & 63, wid = threadIdx.x >> 6;
    if (lane == 0) ls[wid] = s;
    __syncthreads();
    if (threadIdx.x == 0) {
        pooled[bc] = (ls[0] + ls[1] + ls[2] + ls[3]) * (1.0f / 16384.0f);
    }
}

// ---------------------------------------------------------------------------
// Kernel B: noisy top-1 routing (tiny; 16 active threads)
__global__ void route_kernel(const float* __restrict__ pooled,
                             const float* __restrict__ noise,
                             const float* __restrict__ w_gate, const float* __restrict__ b_gate,
                             const float* __restrict__ w_noise, const float* __restrict__ b_noise,
                             int* __restrict__ expert_idx) {
    int b = threadIdx.x;
    if (b >= B_) return;
    float best = -1e30f;
    int bi = 0;
    for (int e = 0; e < E_; e++) {
        float lg = b_gate[e], nz = b_noise[e];
        for (int c = 0; c < C_; c++) {
            float pv = pooled[b * C_ + c];
            lg += pv * w_gate[c * E_ + e];
            nz += pv * w_noise[c * E_ + e];
        }
        float sp = log1pf(expf(nz));           // softplus
        float v = lg + noise[b * E_ + e] * sp; // noisy logit
        if (v > best) { best = v; bi = e; }    // first-max-wins like lax.top_k
    }
    expert_idx[b] = bi;
}

// ---------------------------------------------------------------------------
// Kernel C: build 5 effective conv kernels into [e][ci][tap][co] layout + biases
__global__ void build_w_kernel(const float* __restrict__ w1, const float* __restrict__ w_cd,
                               const float* __restrict__ w_hd, const float* __restrict__ w_vd,
                               const float* __restrict__ w_ad,
                               const float* __restrict__ b1, const float* __restrict__ b_cd,
                               const float* __restrict__ b_hd, const float* __restrict__ b_vd,
                               const float* __restrict__ b_ad,
                               float* __restrict__ wEff, float* __restrict__ biasEff) {
    int gid = blockIdx.x * 256 + threadIdx.x;
    if (gid < E_ * 36864) {
        int e = gid / 36864;
        int r = gid % 36864;
        int ci = r / 576;
        int tap = (r % 576) / 64;
        int co = r % 64;
        int base9 = (co * 64 + ci) * 9;
        int base3 = (co * 64 + ci) * 3;
        float v = 0.f;
        if (e == 0) {
            v = w1[base9 + tap];
        } else if (e == 1) {
            if (tap == 4) {
                float s = 0.f;
                #pragma unroll
                for (int t = 0; t < 9; t++) s += w_cd[base9 + t];
                v = w_cd[base9 + 4] - s;
            } else {
                v = w_cd[base9 + tap];
            }
        } else if (e == 2) {
            int m = tap % 3;
            if (m == 0) v = w_hd[base3 + tap / 3];
            else if (m == 2) v = -w_hd[base3 + tap / 3];
        } else if (e == 3) {
            if (tap < 3) v = w_vd[base3 + tap];
            else if (tap >= 6) v = -w_vd[base3 + tap - 6];
        } else {
            const int PERM[9] = {3, 0, 1, 6, 4, 2, 7, 8, 5};
            v = w_ad[base9 + tap] - w_ad[base9 + PERM[tap]];
        }
        wEff[gid] = v;
    } else if (gid < E_ * 36864 + E_ * 64) {
        int j = gid - E_ * 36864;
        int e = j / 64, co = j % 64;
        const float* bs;
        switch (e) {
            case 0: bs = b1; break;
            case 1: bs = b_cd; break;
            case 2: bs = b_hd; break;
            case 3: bs = b_vd; break;
            default: bs = b_ad; break;
        }
        biasEff[j] = bs[co];
    }
}

// ---------------------------------------------------------------------------
// Kernel D: direct 3x3 conv (selected expert) + exp + per-example sum
// Block: 256 thr. Grid: b(16) x spatial tiles(16x8). Tile = 8 rows x 16 cols,
// all 64 c_out. Thread: 4 c_out x (2 rows x 4 cols).
__global__ __launch_bounds__(256) void conv_kernel(
        const float* __restrict__ x, const float* __restrict__ wEff,
        const float* __restrict__ biasEff, const int* __restrict__ expert_idx,
        float* __restrict__ out, float* __restrict__ Z) {
    int bid = blockIdx.x;
    int b = bid >> 7;
    int tile = bid & 127;
    int tile_r = tile >> 3;   // 0..15, rows tile_r*8..+7
    int tile_c = tile & 7;    // 0..7,  cols tile_c*16..+15
    int t = threadIdx.x;
    int cog = t & 15;         // c_out group: c_outs cog*4..+3
    int pg = t >> 4;          // position group 0..15
    int pr = pg >> 2;         // row pair: tile rows pr*2, pr*2+1
    int pc = pg & 3;          // cols pc*4..+3

    int e = expert_idx[b];
    const float* W = wEff + e * 36864;

    __shared__ __align__(16) float Xs[8][10][20];
    __shared__ __align__(16) float Ws[8][9][64];
    __shared__ float zs[4];

    float acc[4][2][4];
    #pragma unroll
    for (int i = 0; i < 4; i++)
        #pragma unroll
        for (int r = 0; r < 2; r++)
            #pragma unroll
            for (int c = 0; c < 4; c++) acc[i][r][c] = 0.f;

    const float* xb = x + (size_t)b * (C_ * HW_ * HW_);
    int gr0 = tile_r * 8 - 1;   // global row of LDS row 0
    int gc0 = tile_c * 16 - 1;  // global col of LDS col 0

    for (int chunk = 0; chunk < 8; chunk++) {
        // stage X tile: 8 ci x 10 rows x 18 cols (pad to 20)
        for (int j = t; j < 1600; j += 256) {
            int ci = j / 200;
            int rr = (j % 200) / 20;
            int cc = j % 20;
            int grow = gr0 + rr, gcol = gc0 + cc;
            float v = 0.f;
            if (cc < 18 && (unsigned)grow < 128u && (unsigned)gcol < 128u)
                v = xb[((chunk * 8 + ci) * HW_ + grow) * HW_ + gcol];
            Xs[ci][rr][cc] = v;
        }
        // stage W chunk: contiguous 4608 floats ([ci][tap][co] layout)
        {
            const float4* Wsrc = (const float4*)(W + chunk * 4608);
            float4* Wdst = (float4*)&Ws[0][0][0];
            for (int j = t; j < 1152; j += 256) Wdst[j] = Wsrc[j];
        }
        __syncthreads();

        #pragma unroll
        for (int ci = 0; ci < 8; ci++) {
            float4 wv[9];
            #pragma unroll
            for (int k = 0; k < 9; k++)
                wv[k] = *(const float4*)&Ws[ci][k][cog * 4];
            float xr[4][8];
            #pragma unroll
            for (int r = 0; r < 4; r++) {
                *(float4*)&xr[r][0] = *(const float4*)&Xs[ci][pr * 2 + r][pc * 4];
                *(float4*)&xr[r][4] = *(const float4*)&Xs[ci][pr * 2 + r][pc * 4 + 4];
            }
            #pragma unroll
            for (int r = 0; r < 2; r++)
                #pragma unroll
                for (int dr = 0; dr < 3; dr++)
                    #pragma unroll
                    for (int dc = 0; dc < 3; dc++) {
                        float4 w = wv[dr * 3 + dc];
                        #pragma unroll
                        for (int c = 0; c < 4; c++) {
                            float xv = xr[r + dr][c + dc];
                            acc[0][r][c] = fmaf(w.x, xv, acc[0][r][c]);
                            acc[1][r][c] = fmaf(w.y, xv, acc[1][r][c]);
                            acc[2][r][c] = fmaf(w.z, xv, acc[2][r][c]);
                            acc[3][r][c] = fmaf(w.w, xv, acc[3][r][c]);
                        }
                    }
        }
        __syncthreads();
    }

    // epilogue: bias, exp, store, block-reduce sum into Z[b]
    float bias[4];
    *(float4*)bias = *(const float4*)&biasEff[e * 64 + cog * 4];
    float bsum = 0.f;
    #pragma unroll
    for (int co = 0; co < 4; co++) {
        #pragma unroll
        for (int r = 0; r < 2; r++) {
            float4 v;
            v.x = __expf(acc[co][r][0] + bias[co]);
            v.y = __expf(acc[co][r][1] + bias[co]);
            v.z = __expf(acc[co][r][2] + bias[co]);
            v.w = __expf(acc[co][r][3] + bias[co]);
            bsum += v.x + v.y + v.z + v.w;
            int grow = tile_r * 8 + pr * 2 + r;
            int gcol = tile_c * 16 + pc * 4;
            *(float4*)&out[(((size_t)b * C_ + cog * 4 + co) * HW_ + grow) * HW_ + gcol] = v;
        }
    }
    for (int off = 32; off; off >>= 1) bsum += __shfl_down(bsum, off, 64);
    if ((t & 63) == 0) zs[t >> 6] = bsum;
    __syncthreads();
    if (t == 0) atomicAdd(&Z[b], zs[0] + zs[1] + zs[2] + zs[3]);
}

// ---------------------------------------------------------------------------
// Kernel E: out *= 1/Z[b]
__global__ void scale_kernel(float* __restrict__ out, const float* __restrict__ Z) {
    int gid = blockIdx.x * 256 + threadIdx.x;  // over float4s, 4194304 total
    int b = gid >> 18;                          // 262144 float4 per example
    __shared__ float sinv;
    if (threadIdx.x == 0) sinv = 1.0f / Z[b];
    __syncthreads();
    float4 v = ((float4*)out)[gid];
    v.x *= sinv; v.y *= sinv; v.z *= sinv; v.w *= sinv;
    ((float4*)out)[gid] = v;
}

// ---------------------------------------------------------------------------
extern "C" void kernel_launch(void* const* d_in, const int* in_sizes, int n_in,
                              void* d_out, int out_size, void* d_ws, size_t ws_size,
                              hipStream_t stream) {
    const float* x       = (const float*)d_in[0];
    const float* noise   = (const float*)d_in[1];
    const float* w_gate  = (const float*)d_in[2];
    const float* b_gate  = (const float*)d_in[3];
    const float* w_noise = (const float*)d_in[4];
    const float* b_noise = (const float*)d_in[5];
    const float* w1      = (const float*)d_in[6];
    const float* b1      = (const float*)d_in[7];
    const float* w_cd    = (const float*)d_in[8];
    const float* b_cd    = (const float*)d_in[9];
    const float* w_hd    = (const float*)d_in[10];
    const float* b_hd    = (const float*)d_in[11];
    const float* w_vd    = (const float*)d_in[12];
    const float* b_vd    = (const float*)d_in[13];
    const float* w_ad    = (const float*)d_in[14];
    const float* b_ad    = (const float*)d_in[15];

    float* ws = (float*)d_ws;
    float* wEff    = ws + WS_WEFF;
    float* biasEff = ws + WS_BIAS;
    float* pooled  = ws + WS_POOL;
    float* Zbuf    = ws + WS_Z;
    int*   eidx    = (int*)(ws + WS_EIDX);
    float* out     = (float*)d_out;

    // zero the per-example softmax denominators (ws is poisoned each call)
    hipMemsetAsync(Zbuf, 0, B_ * sizeof(float), stream);

    pool_kernel<<<B_ * C_, 256, 0, stream>>>(x, pooled);
    route_kernel<<<1, 64, 0, stream>>>(pooled, noise, w_gate, b_gate, w_noise, b_noise, eidx);
    build_w_kernel<<<(E_ * 36864 + E_ * 64 + 255) / 256, 256, 0, stream>>>(
        w1, w_cd, w_hd, w_vd, w_ad, b1, b_cd, b_hd, b_vd, b_ad, wEff, biasEff);
    conv_kernel<<<B_ * 128, 256, 0, stream>>>(x, wEff, biasEff, eidx, out, Zbuf);
    scale_kernel<<<16384, 256, 0, stream>>>(out, Zbuf);
}

// Round 3
// 229.614 us; speedup vs baseline: 1.7600x; 1.7600x over previous
//
#include <hip/hip_runtime.h>
#include <math.h>

#define B_  16
#define C_  64
#define HW_ 128
#define E_  5

typedef __bf16  bf16x8 __attribute__((ext_vector_type(8)));
typedef float   f32x4  __attribute__((ext_vector_type(4)));

// ---- ws byte offsets ----
// wEffB: [e(5)][g(2)][tap(9)][q(4)][co(64)][j(8)] ushort = 184320 shorts = 368640 B
#define WS_WEFFB   0
#define WS_BIAS    368640      // float[5*64] -> ends 369920
#define WS_POOL    369920      // float[16*64] (zeroed each call) -> 374016
#define WS_Z       374016      // float[16] (zeroed each call) -> 374080
#define WS_EIDX    374080      // int[16] -> 374144
#define WS_XT      374144      // bf16 x_t [b][row][col][ci] = 33554432 B -> 33928576
#define WS_EXP     33928576    // bf16 exp [b][co][row][col] = 33554432 B -> 67483008
#define WS_NEED_A  67483008ull
#define WS_NEED_B  33928576ull

static __device__ __forceinline__ unsigned short f2bf(float f) {
    unsigned int u = __float_as_uint(f);
    unsigned int r = (u + 0x7fffu + ((u >> 16) & 1u)) >> 16;  // RNE
    return (unsigned short)r;
}

// ---------------------------------------------------------------------------
// Kernel 1: fused transpose (fp32 NCHW -> bf16 NHWC) + global-mean pooling
// grid: (b*128 + row) = 2048 blocks, 256 thr
__global__ __launch_bounds__(256) void transpose_pool_kernel(
        const float* __restrict__ x, unsigned short* __restrict__ x_t,
        float* __restrict__ pooled) {
    int bid = blockIdx.x;
    int b = bid >> 7, row = bid & 127;
    int t = threadIdx.x;
    int wave = t >> 6, l = t & 63;
    int half = l >> 5;        // which of 2 ci per iter
    int c4 = l & 31;          // float4 column chunk

    __shared__ unsigned short T[128][72];   // [col][ci], padded (72*2=144 B rows, 16B aligned)

    const float* xb = x + (size_t)b * (64 * 16384) + row * 128;

    #pragma unroll
    for (int it = 0; it < 8; it++) {
        int ci = wave * 16 + it * 2 + half;
        float4 v = *(const float4*)(xb + (size_t)ci * 16384 + c4 * 4);
        float p = v.x + v.y + v.z + v.w;
        p += __shfl_down(p, 16, 32);
        p += __shfl_down(p, 8, 32);
        p += __shfl_down(p, 4, 32);
        p += __shfl_down(p, 2, 32);
        p += __shfl_down(p, 1, 32);
        if (c4 == 0) atomicAdd(&pooled[b * 64 + ci], p * (1.0f / 16384.0f));
        int colb = c4 * 4;
        T[colb + 0][ci] = f2bf(v.x);
        T[colb + 1][ci] = f2bf(v.y);
        T[colb + 2][ci] = f2bf(v.z);
        T[colb + 3][ci] = f2bf(v.w);
    }
    __syncthreads();

    unsigned short* dst = x_t + ((size_t)(b * 128 + row) * 128) * 64;
    #pragma unroll
    for (int k = 0; k < 4; k++) {
        int chunk = t + k * 256;          // 1024 chunks of 16B
        int col = chunk >> 3, c8 = chunk & 7;
        uint4 vv = *(const uint4*)&T[col][c8 * 8];
        *(uint4*)(dst + col * 64 + c8 * 8) = vv;
    }
}

// ---------------------------------------------------------------------------
// Kernel 2: noisy top-1 routing
__global__ void route_kernel(const float* __restrict__ pooled,
                             const float* __restrict__ noise,
                             const float* __restrict__ w_gate, const float* __restrict__ b_gate,
                             const float* __restrict__ w_noise, const float* __restrict__ b_noise,
                             int* __restrict__ expert_idx) {
    int b = threadIdx.x;
    if (b >= B_) return;
    float best = -1e30f;
    int bi = 0;
    for (int e = 0; e < E_; e++) {
        float lg = b_gate[e], nz = b_noise[e];
        for (int c = 0; c < C_; c++) {
            float pv = pooled[b * C_ + c];
            lg += pv * w_gate[c * E_ + e];
            nz += pv * w_noise[c * E_ + e];
        }
        float sp = log1pf(expf(nz));
        float v = lg + noise[b * E_ + e] * sp;
        if (v > best) { best = v; bi = e; }
    }
    expert_idx[b] = bi;
}

// ---------------------------------------------------------------------------
// Kernel 3: build bf16 effective weights in MFMA A-fragment order
// layout: [e][g(2)][tap(9)][q(4)][co(64)][j(8)], ci = g*32 + q*8 + j
// per-expert = 36864 shorts, per-g = 18432 shorts
__global__ void build_w_kernel(const float* __restrict__ w1, const float* __restrict__ w_cd,
                               const float* __restrict__ w_hd, const float* __restrict__ w_vd,
                               const float* __restrict__ w_ad,
                               const float* __restrict__ b1, const float* __restrict__ b_cd,
                               const float* __restrict__ b_hd, const float* __restrict__ b_vd,
                               const float* __restrict__ b_ad,
                               unsigned short* __restrict__ wEffB, float* __restrict__ biasEff) {
    int gid = blockIdx.x * 256 + threadIdx.x;
    if (gid < E_ * 36864) {
        int e   = gid / 36864;
        int r   = gid % 36864;
        int g   = r / 18432;
        int r2  = r % 18432;
        int tap = r2 / 2048;
        int r3  = r2 % 2048;
        int q   = r3 / 512;
        int r4  = r3 % 512;
        int co  = r4 / 8;
        int j   = r4 % 8;
        int ci = g * 32 + q * 8 + j;
        int base9 = (co * 64 + ci) * 9;
        int base3 = (co * 64 + ci) * 3;
        float v = 0.f;
        if (e == 0) {
            v = w1[base9 + tap];
        } else if (e == 1) {
            if (tap == 4) {
                float s = 0.f;
                #pragma unroll
                for (int k = 0; k < 9; k++) s += w_cd[base9 + k];
                v = w_cd[base9 + 4] - s;
            } else {
                v = w_cd[base9 + tap];
            }
        } else if (e == 2) {
            int m = tap % 3;
            if (m == 0) v = w_hd[base3 + tap / 3];
            else if (m == 2) v = -w_hd[base3 + tap / 3];
        } else if (e == 3) {
            if (tap < 3) v = w_vd[base3 + tap];
            else if (tap >= 6) v = -w_vd[base3 + tap - 6];
        } else {
            const int PERM[9] = {3, 0, 1, 6, 4, 2, 7, 8, 5};
            v = w_ad[base9 + tap] - w_ad[base9 + PERM[tap]];
        }
        wEffB[gid] = f2bf(v);
    } else if (gid < E_ * 36864 + E_ * 64) {
        int jj = gid - E_ * 36864;
        int e = jj / 64, co = jj % 64;
        const float* bs;
        switch (e) {
            case 0: bs = b1; break;
            case 1: bs = b_cd; break;
            case 2: bs = b_hd; break;
            case 3: bs = b_vd; break;
            default: bs = b_ad; break;
        }
        biasEff[jj] = bs[co];
    }
}

// ---------------------------------------------------------------------------
// Kernel 4: MFMA implicit-GEMM conv + exp + store + per-example Z sum
// grid: b(16) x rowgroup(32) x colhalf(2) = 1024 blocks, 256 thr (4 waves)
// block tile: 64 co x (4 rows x 64 cols). wave: 64 co x (1 row x 64 cols).
// direct_f32 != 0: write fp32 exp to outf (final layout); else bf16 to expw.
__global__ __launch_bounds__(256) void conv_mfma_kernel(
        const unsigned short* __restrict__ x_t, const unsigned short* __restrict__ wEffB,
        const float* __restrict__ biasEff, const int* __restrict__ expert_idx,
        unsigned short* __restrict__ expw, float* __restrict__ outf,
        float* __restrict__ Z, int direct_f32) {
    int bid = blockIdx.x;
    int b = bid >> 6;
    int rem = bid & 63;
    int rg = rem >> 1;        // 0..31, out rows rg*4..+3
    int ch = rem & 1;         // 0/1,  out cols ch*64..+63

    int t = threadIdx.x;
    int wave = t >> 6;        // out-row-local 0..3
    int lane = t & 63;
    int ln = lane & 15;
    int q = lane >> 4;

    int e = expert_idx[b];

    __shared__ __align__(16) unsigned short A_lds[9 * 4 * 66 * 8];  // 38016 B
    __shared__ __align__(16) unsigned short Xs[6 * 4 * 68 * 8];     // 26112 B
    __shared__ float zs[4];

    f32x4 acc[4][4];
    #pragma unroll
    for (int i = 0; i < 4; i++)
        #pragma unroll
        for (int jn = 0; jn < 4; jn++)
            acc[i][jn] = (f32x4){0.f, 0.f, 0.f, 0.f};

    const unsigned short* xb = x_t + (size_t)b * (128 * 128 * 64);
    const unsigned short* we = wEffB + (size_t)e * 36864;

    for (int g = 0; g < 2; g++) {
        // --- stage A: 2304 chunks of 16B ([tap][q][co][j], contiguous) ---
        const uint4* asrc = (const uint4*)(we + g * 18432);
        for (int j = t; j < 2304; j += 256) {
            int slotrow = j >> 6;     // tap*4 + q
            int m = j & 63;
            *(uint4*)&A_lds[(slotrow * 66 + m) * 8] = asrc[j];
        }
        // --- stage X: 6 rows x 66 cols x (4 q-chunks of 8 ci) ---
        for (int j = t; j < 1584; j += 256) {
            int xr = j / 264;
            int r2 = j % 264;
            int col = r2 >> 2;
            int qq = r2 & 3;
            int irow = rg * 4 - 1 + xr;
            int icol = ch * 64 - 1 + col;
            uint4 v = make_uint4(0, 0, 0, 0);
            if ((unsigned)irow < 128u && (unsigned)icol < 128u)
                v = *(const uint4*)(xb + ((size_t)irow * 128 + icol) * 64 + g * 32 + qq * 8);
            *(uint4*)&Xs[((xr * 4 + qq) * 68 + col) * 8] = v;
        }
        __syncthreads();

        #pragma unroll
        for (int tap = 0; tap < 9; tap++) {
            int dr = tap / 3, dc = tap % 3;
            bf16x8 af[4], bfr[4];
            #pragma unroll
            for (int mt = 0; mt < 4; mt++)
                af[mt] = *(const bf16x8*)&A_lds[((tap * 4 + q) * 66 + mt * 16 + ln) * 8];
            int xr = wave + dr;
            #pragma unroll
            for (int t4 = 0; t4 < 4; t4++)
                bfr[t4] = *(const bf16x8*)&Xs[((xr * 4 + q) * 68 + t4 * 16 + ln + dc) * 8];
            #pragma unroll
            for (int mt = 0; mt < 4; mt++)
                #pragma unroll
                for (int t4 = 0; t4 < 4; t4++)
                    acc[mt][t4] = __builtin_amdgcn_mfma_f32_16x16x32_bf16(
                        af[mt], bfr[t4], acc[mt][t4], 0, 0, 0);
        }
        __syncthreads();
    }

    // --- epilogue: bias + exp + store + Z reduction ---
    int orow = rg * 4 + wave;
    float bsum = 0.f;
    size_t obase = (size_t)b * (64 * 16384);
    #pragma unroll
    for (int mt = 0; mt < 4; mt++) {
        float4 bias4 = *(const float4*)(biasEff + e * 64 + mt * 16 + q * 4);
        const float* bp = (const float*)&bias4;
        #pragma unroll
        for (int r = 0; r < 4; r++) {
            int co = mt * 16 + q * 4 + r;
            size_t cb = obase + (size_t)co * 16384 + (size_t)orow * 128;
            #pragma unroll
            for (int t4 = 0; t4 < 4; t4++) {
                float ev = __expf(acc[mt][t4][r] + bp[r]);
                bsum += ev;
                int ocol = ch * 64 + t4 * 16 + ln;
                if (direct_f32) outf[cb + ocol] = ev;
                else            expw[cb + ocol] = f2bf(ev);
            }
        }
    }
    for (int off = 32; off; off >>= 1) bsum += __shfl_down(bsum, off, 64);
    if (lane == 0) zs[wave] = bsum;
    __syncthreads();
    if (t == 0) atomicAdd(&Z[b], zs[0] + zs[1] + zs[2] + zs[3]);
}

// ---------------------------------------------------------------------------
// Kernel 5a: out = bf16_exp * (1/Z[b]) -> fp32 (Mode A)
__global__ __launch_bounds__(256) void scale_bf16_kernel(
        const unsigned short* __restrict__ expw, const float* __restrict__ Z,
        float* __restrict__ out) {
    int gid = blockIdx.x * 256 + threadIdx.x;     // 2,097,152 threads; 8 elems each
    int b = gid >> 17;                            // 131072 uint4-threads per example
    __shared__ float sinv;
    if (threadIdx.x == 0) sinv = 1.0f / Z[b];
    __syncthreads();
    uint4 r = ((const uint4*)expw)[gid];
    float4 o0, o1;
    o0.x = __uint_as_float(r.x << 16) * sinv;
    o0.y = __uint_as_float(r.x & 0xffff0000u) * sinv;
    o0.z = __uint_as_float(r.y << 16) * sinv;
    o0.w = __uint_as_float(r.y & 0xffff0000u) * sinv;
    o1.x = __uint_as_float(r.z << 16) * sinv;
    o1.y = __uint_as_float(r.z & 0xffff0000u) * sinv;
    o1.z = __uint_as_float(r.w << 16) * sinv;
    o1.w = __uint_as_float(r.w & 0xffff0000u) * sinv;
    ((float4*)out)[gid * 2] = o0;
    ((float4*)out)[gid * 2 + 1] = o1;
}

// Kernel 5b: in-place out *= 1/Z[b] (Mode B)
__global__ __launch_bounds__(256) void scale_inplace_kernel(
        float* __restrict__ out, const float* __restrict__ Z) {
    int gid = blockIdx.x * 256 + threadIdx.x;  // over float4s, 4,194,304 total
    int b = gid >> 18;                          // 262144 float4 per example
    __shared__ float sinv;
    if (threadIdx.x == 0) sinv = 1.0f / Z[b];
    __syncthreads();
    float4 v = ((float4*)out)[gid];
    v.x *= sinv; v.y *= sinv; v.z *= sinv; v.w *= sinv;
    ((float4*)out)[gid] = v;
}

// ---------------------------------------------------------------------------
extern "C" void kernel_launch(void* const* d_in, const int* in_sizes, int n_in,
                              void* d_out, int out_size, void* d_ws, size_t ws_size,
                              hipStream_t stream) {
    const float* x       = (const float*)d_in[0];
    const float* noise   = (const float*)d_in[1];
    const float* w_gate  = (const float*)d_in[2];
    const float* b_gate  = (const float*)d_in[3];
    const float* w_noise = (const float*)d_in[4];
    const float* b_noise = (const float*)d_in[5];
    const float* w1      = (const float*)d_in[6];
    const float* b1      = (const float*)d_in[7];
    const float* w_cd    = (const float*)d_in[8];
    const float* b_cd    = (const float*)d_in[9];
    const float* w_hd    = (const float*)d_in[10];
    const float* b_hd    = (const float*)d_in[11];
    const float* w_vd    = (const float*)d_in[12];
    const float* b_vd    = (const float*)d_in[13];
    const float* w_ad    = (const float*)d_in[14];
    const float* b_ad    = (const float*)d_in[15];

    char* ws = (char*)d_ws;
    unsigned short* wEffB   = (unsigned short*)(ws + WS_WEFFB);
    float*          biasEff = (float*)(ws + WS_BIAS);
    float*          pooled  = (float*)(ws + WS_POOL);
    float*          Zbuf    = (float*)(ws + WS_Z);
    int*            eidx    = (int*)(ws + WS_EIDX);
    unsigned short* x_t     = (unsigned short*)(ws + WS_XT);
    unsigned short* expw    = (unsigned short*)(ws + WS_EXP);

    float* out = (float*)d_out;
    int mode_a = (ws_size >= WS_NEED_A) ? 1 : 0;   // constant across calls

    // zero pooled + Z (contiguous 4160 B)
    hipMemsetAsync(pooled, 0, 4160, stream);

    transpose_pool_kernel<<<B_ * 128, 256, 0, stream>>>(x, x_t, pooled);
    route_kernel<<<1, 64, 0, stream>>>(pooled, noise, w_gate, b_gate, w_noise, b_noise, eidx);
    build_w_kernel<<<(E_ * 36864 + E_ * 64 + 255) / 256, 256, 0, stream>>>(
        w1, w_cd, w_hd, w_vd, w_ad, b1, b_cd, b_hd, b_vd, b_ad, wEffB, biasEff);
    conv_mfma_kernel<<<1024, 256, 0, stream>>>(x_t, wEffB, biasEff, eidx,
                                               expw, out, Zbuf, mode_a ? 0 : 1);
    if (mode_a)
        scale_bf16_kernel<<<8192, 256, 0, stream>>>(expw, Zbuf, out);
    else
        scale_inplace_kernel<<<16384, 256, 0, stream>>>(out, Zbuf);
}